// Round 8
// baseline (215.767 us; speedup 1.0000x reference)
//
#include <hip/hip_runtime.h>
#include <hip/hip_bf16.h>

typedef __attribute__((ext_vector_type(8))) short bf16x8;
typedef __attribute__((ext_vector_type(4))) float f32x4;
typedef __attribute__((ext_vector_type(16))) float f32x16;

#define DM   1024
#define SEQ  2048
#define NB   2
#define NH   16
#define MR   (NB*SEQ)            /* 4096 rows of the flattened [B*S, D] matrices */

#define SMK  (MR*DM)             /* 4194304 elements per [4096,1024] tensor */
#define W1M  (DM*DM)             /* 1048576 elements per weight matrix */

/* 0.125 * log2(e): folded into Q projection so attention uses exp2 directly */
#define QSCALE 0.18033688011112042f

/* workspace layout, in bf16 (ushort) units.
 * QB/KB/VB (bf16 inputs) are dead after gemm_qkv -> reused as split-K partial-O
 * buffers (split s -> ws + s*SMK). WQ/WK/WV dead after gemm_qkv -> l partials (f32).
 * concat (OFF_CC) aliases QB; combine_splits updates it in place. */
#define OFF_QB  ((size_t)0)
#define OFF_KB  ((size_t)SMK)
#define OFF_VB  ((size_t)(2*(size_t)SMK))
#define OFF_WQ  ((size_t)(3*(size_t)SMK))                       /* WK=+W1M, WV=+2*W1M, WO=+3*W1M */
#define OFF_WO  ((size_t)(3*(size_t)SMK + 3*(size_t)W1M))
#define OFF_QP  ((size_t)(3*(size_t)SMK + 4*(size_t)W1M))
#define OFF_KP  ((size_t)(4*(size_t)SMK + 4*(size_t)W1M))
#define OFF_VP  ((size_t)(5*(size_t)SMK + 4*(size_t)W1M))       /* V^T: [DM][MR] */
#define OFF_CC  ((size_t)0)

__device__ __forceinline__ unsigned short f2bf(float f) {
  union { __hip_bfloat16 b; unsigned short u; } cv;
  cv.b = __float2bfloat16(f);
  return cv.u;
}

__device__ __forceinline__ float bf2f(unsigned short u) {
  union { unsigned int i; float f; } cv;
  cv.i = (unsigned int)u << 16;
  return cv.f;
}

/* v_cvt_pk_bf16_f32: packs (lo,hi) floats into one u32 of 2 bf16 */
__device__ __forceinline__ unsigned int cvtpk_bf16(float lo, float hi) {
  unsigned int r;
  asm("v_cvt_pk_bf16_f32 %0, %1, %2" : "=v"(r) : "v"(lo), "v"(hi));
  return r;
}

/* v_permlane32_swap_b32: a.upper32lanes <-> b.lower32lanes (both results used) */
__device__ __forceinline__ void plane32_swap(unsigned int& a, unsigned int& b) {
  asm("v_permlane32_swap_b32 %0, %1" : "+v"(a), "+v"(b));
}

/* ---------------- f32 -> bf16 converts, z-batched ---------------- */
__global__ __launch_bounds__(256) void cvt_inputs(const float* __restrict__ q,
                                                  const float* __restrict__ k,
                                                  const float* __restrict__ v,
                                                  unsigned short* __restrict__ dst) {
  const int z = blockIdx.y;
  const float* src = (z == 0) ? q : ((z == 1) ? k : v);
  int i = blockIdx.x * 256 + threadIdx.x;          /* SMK/4 per tensor */
  float4 val = reinterpret_cast<const float4*>(src)[i];
  ushort4 o;
  o.x = f2bf(val.x); o.y = f2bf(val.y); o.z = f2bf(val.z); o.w = f2bf(val.w);
  reinterpret_cast<ushort4*>(dst + (size_t)z * SMK)[i] = o;
}

__global__ __launch_bounds__(256) void cvt_weights(const float* __restrict__ wq,
                                                   const float* __restrict__ wk,
                                                   const float* __restrict__ wv,
                                                   const float* __restrict__ wo,
                                                   unsigned short* __restrict__ dst) {
  const int z = blockIdx.y;
  const float* src = (z == 0) ? wq : ((z == 1) ? wk : ((z == 2) ? wv : wo));
  int i = blockIdx.x * 256 + threadIdx.x;          /* W1M/4 per tensor */
  float4 val = reinterpret_cast<const float4*>(src)[i];
  ushort4 o;
  o.x = f2bf(val.x); o.y = f2bf(val.y); o.z = f2bf(val.z); o.w = f2bf(val.w);
  reinterpret_cast<ushort4*>(dst + (size_t)z * W1M)[i] = o;
}

/* ---------------- async global->LDS, 16B per lane ---------------- */
__device__ __forceinline__ void gload_lds16(const void* g, void* l) {
  __builtin_amdgcn_global_load_lds(
      (const __attribute__((address_space(1))) unsigned int*)g,
      (__attribute__((address_space(3))) unsigned int*)l,
      16, 0, 0);
}

/* ---------------- BMxBN tile GEMM body, C = (A * Bt^T + bias) * scale ----------------
 * A: [M][K] bf16 row-major, Bt: [N][K] bf16 row-major (i.e. y = x @ W.T).
 * 4 waves as 2x2, wave tile (BM/2)x(BN/2). 3-buffer LDS, depth-2 prefetch,
 * raw s_barrier + counted vmcnt (never drains to 0 mid-loop). */
template<int BM, int BN, bool OUT_BF16, bool BIAS_ROW>
__device__ __forceinline__ void gemm_bt_body(unsigned short* __restrict__ As,
                                             unsigned short* __restrict__ Bs,
                                             const unsigned short* __restrict__ A,
                                             const unsigned short* __restrict__ Bt,
                                             const float* __restrict__ bias,
                                             void* __restrict__ Cv,
                                             int N, int K, float scale,
                                             int brow, int bcol) {
  constexpr int MREP = BM / 32;
  constexpr int NREP = BN / 32;
  constexpr int LPS  = BM / 64 + BN / 64;   /* gload_lds per wave per stage */
  const int tid  = threadIdx.x;
  const int lane = tid & 63;
  const int w    = tid >> 6;
  const int wr   = w >> 1, wc = w & 1;

  f32x4 acc[MREP][NREP];
#pragma unroll
  for (int m = 0; m < MREP; m++)
#pragma unroll
    for (int n = 0; n < NREP; n++) acc[m][n] = (f32x4){0.f, 0.f, 0.f, 0.f};

  const int srow = lane >> 2;        /* 0..15 row within a 16-row chunk */
  const int scol = (lane & 3) * 8;   /* 0,8,16,24 bf16 col */

  auto stage = [&](int buf, int k0) {
#pragma unroll
    for (int c = w; c < BM / 16; c += 4)
      gload_lds16(A + (size_t)(brow + c * 16 + srow) * K + k0 + scol,
                  (char*)As + (size_t)buf * BM * 64 + c * 1024);
#pragma unroll
    for (int c = w; c < BN / 16; c += 4)
      gload_lds16(Bt + (size_t)(bcol + c * 16 + srow) * K + k0 + scol,
                  (char*)Bs + (size_t)buf * BN * 64 + c * 1024);
  };

  stage(0, 0);
  stage(1, 32);

  const int nk = K / 32;
  const int lrow_a = wr * (BM / 2) + (lane & 15);
  const int lrow_b = wc * (BN / 2) + (lane & 15);
  const int lcol   = (lane >> 4) * 8;

  int b0 = 0;
  for (int kt = 0; kt < nk; ++kt) {
    if (kt + 1 < nk) {
      if constexpr (LPS == 4) asm volatile("s_waitcnt vmcnt(4)" ::: "memory");
      else                    asm volatile("s_waitcnt vmcnt(3)" ::: "memory");
    } else {
      asm volatile("s_waitcnt vmcnt(0)" ::: "memory");
    }
    __builtin_amdgcn_s_barrier();
    __builtin_amdgcn_sched_barrier(0);
    if (kt + 2 < nk) {
      int bn = b0 + 2; if (bn >= 3) bn -= 3;
      stage(bn, (kt + 2) * 32);
    }
    bf16x8 a[MREP], b[NREP];
#pragma unroll
    for (int m = 0; m < MREP; m++)
      a[m] = *(const bf16x8*)&As[(size_t)b0 * BM * 32 + (lrow_a + m * 16) * 32 + lcol];
#pragma unroll
    for (int n = 0; n < NREP; n++)
      b[n] = *(const bf16x8*)&Bs[(size_t)b0 * BN * 32 + (lrow_b + n * 16) * 32 + lcol];
    __builtin_amdgcn_s_setprio(1);
#pragma unroll
    for (int m = 0; m < MREP; m++)
#pragma unroll
      for (int n = 0; n < NREP; n++)
        acc[m][n] = __builtin_amdgcn_mfma_f32_16x16x32_bf16(a[m], b[n], acc[m][n], 0, 0, 0);
    __builtin_amdgcn_s_setprio(0);
    b0 = (b0 == 2) ? 0 : b0 + 1;
  }

  const int crow0 = brow + wr * (BM / 2);
  const int ccol0 = bcol + wc * (BN / 2);
  const int rsub  = (lane >> 4) * 4;
  const int csub  = lane & 15;
#pragma unroll
  for (int m = 0; m < MREP; m++)
#pragma unroll
    for (int n = 0; n < NREP; n++) {
      int col = ccol0 + n * 16 + csub;
      float bcol_v = BIAS_ROW ? 0.f : bias[col];
#pragma unroll
      for (int qq = 0; qq < 4; qq++) {
        int row = crow0 + m * 16 + rsub + qq;
        float bb = BIAS_ROW ? bias[row] : bcol_v;
        float v = (acc[m][n][qq] + bb) * scale;
        if (OUT_BF16)
          ((unsigned short*)Cv)[(size_t)row * N + col] = f2bf(v);
        else
          ((float*)Cv)[(size_t)row * N + col] = v;
      }
    }
}

/* Q (prescaled by QSCALE), K, and V^T projections, z-batched: 768 blocks = 3/CU. */
__global__ __launch_bounds__(256) void gemm_qkv(unsigned short* ws,
                                                const float* __restrict__ bq,
                                                const float* __restrict__ bk,
                                                const float* __restrict__ bv) {
  __shared__ unsigned short As[3 * 128 * 32];
  __shared__ unsigned short Bs[3 * 128 * 32];
  const int z = blockIdx.z;
  const int bid = blockIdx.x;
  if (z < 2) {
    /* [MR][DM] = [MR][DM] @ W^T : grid 8 x 32 */
    int bx = bid & 7, by = bid >> 3;
    gemm_bt_body<128, 128, true, false>(
        As, Bs,
        ws + OFF_QB + (size_t)z * SMK, ws + OFF_WQ + (size_t)z * W1M,
        z ? bk : bq, ws + OFF_QP + (size_t)z * SMK,
        DM, DM, z ? 1.f : QSCALE, by * 128, bx * 128);
  } else {
    /* V^T [DM][MR] = Wv @ v^T : grid 32 x 8, bias per row */
    int bx = bid & 31, by = bid >> 5;
    gemm_bt_body<128, 128, true, true>(
        As, Bs,
        ws + OFF_WQ + 2 * W1M, ws + OFF_VB,
        bv, ws + OFF_VP,
        MR, DM, 1.f, by * 128, bx * 128);
  }
}

/* Output projection: 64x128 tile -> 512 blocks, 36KB LDS. */
__global__ __launch_bounds__(256) void gemm_out(const unsigned short* __restrict__ ws,
                                                const float* __restrict__ bo,
                                                float* __restrict__ out) {
  __shared__ unsigned short As[3 * 64 * 32];
  __shared__ unsigned short Bs[3 * 128 * 32];
  gemm_bt_body<64, 128, false, false>(
      As, Bs,
      ws + OFF_CC, ws + OFF_WO, bo, out,
      DM, DM, 1.f, blockIdx.y * 64, blockIdx.x * 128);
}

/* ---------------- flash attention v6: split-K x3 as independent blocks ----------------
 * grid: 768 flat (XCD-swizzled: 96 consecutive = 4 bh per XCD). block: 256 = 4 waves.
 * Block = (bh, qblk of 256 q-rows, split s of ~11 k-tiles). Wave owns 64 q-rows
 * (2 q-sets of 32, q = lane&31): each K/V b128 read feeds 4 MFMAs. 48KB LDS
 * (3 x 16KB bufs, depth-2 prefetch, counted vmcnt) -> 3 blocks/CU = 3 waves/SIMD,
 * with co-resident blocks desynced so VALU/MFMA/LDS pipes overlap across blocks.
 * No-max softmax (P = exp2(s), shift-invariant, bounded scores) -> split partials
 * combine linearly: unnormalized O (bf16) to ws + s*SMK, l (f32, via ones-MFMA,
 * no VALU reduction) to the dead WQ region. combine_splits finishes. */
__global__ __launch_bounds__(256, 3) void flash_attn(unsigned short* ws) {
  __shared__ __align__(16) unsigned char smem[49152];   /* 3 bufs x 16KB */

  const int tid  = threadIdx.x;
  const int lane = tid & 63;
  const int wsub = tid >> 6;        /* 0..3 -> q-subtile */
  const int q    = lane & 31;
  const int hi   = lane >> 5;
  const int swq  = q & 7;
  const int bid  = blockIdx.x;      /* 0..767 */
  const int swzb = (bid & 7) * 96 + (bid >> 3);   /* XCD-contiguous remap */
  const int bh   = swzb / 24;       /* 0..31 (24 blocks per bh) */
  const int r24  = swzb % 24;
  const int qblk = r24 / 3;         /* 0..7, 256 q-rows each */
  const int s    = r24 % 3;         /* k-split: tiles [s*11, s*11+nt) */
  const int b    = bh >> 4, h = bh & 15;
  const int kt0  = s * 11;
  const int nt   = (s == 2) ? 10 : 11;

  const unsigned short* Qp = ws + OFF_QP;
  const unsigned short* Kp = ws + OFF_KP;
  const unsigned short* Vp = ws + OFF_VP;

  const unsigned short* Kg = Kp + (size_t)(b * SEQ) * DM + h * 64;          /* +row*DM */
  const unsigned short* Vg = Vp + (size_t)(h * 64) * MR + (size_t)b * SEQ;  /* +row*MR */

  /* Q B-fragments, 2 q-sets (col=q, k=hi*8+i within 16-d chunk c), prescaled */
  bf16x8 bqf[2][4];
#pragma unroll
  for (int s2 = 0; s2 < 2; s2++) {
    const unsigned short* qrow =
        Qp + (size_t)(b * SEQ + qblk * 256 + wsub * 64 + s2 * 32 + q) * DM + h * 64;
#pragma unroll
    for (int c = 0; c < 4; c++)
      bqf[s2][c] = *(const bf16x8*)(qrow + c * 16 + hi * 8);
  }

  const bf16x8 kOnes = {16256, 16256, 16256, 16256, 16256, 16256, 16256, 16256}; /* bf16 1.0 */

  f32x16 o_acc[2][2];
  f32x16 o_l[2];
#pragma unroll
  for (int s2 = 0; s2 < 2; s2++) {
#pragma unroll
    for (int r = 0; r < 16; r++) o_l[s2][r] = 0.f;
#pragma unroll
    for (int dt = 0; dt < 2; dt++)
#pragma unroll
      for (int r = 0; r < 16; r++) o_acc[s2][dt][r] = 0.f;
  }

  /* stage k-tile kt into buffer `buf`; 4 waves split the 512 16B-slots */
  auto stage = [&](int buf, int kt) {
    const unsigned short* Kt = Kg + (size_t)kt * 64 * DM;
    const unsigned short* Vt = Vg + kt * 64;
    char* base = (char*)smem + (size_t)buf * 16384;
#pragma unroll
    for (int i = 0; i < 2; i++) {
      int slot = wsub * 128 + i * 64 + lane;   /* 16B slot 0..511 */
      int srow = slot >> 3;                    /* 0..63 */
      int gch  = (slot & 7) ^ (srow & 7);      /* inverse swizzle on global source */
      gload_lds16(Kt + (size_t)srow * DM + gch * 8, base + slot * 16);
      gload_lds16(Vt + (size_t)srow * MR + gch * 8, base + 8192 + slot * 16);
    }
  };

  stage(0, kt0);
  stage(1, kt0 + 1);

  int bcur = 0;
  for (int t = 0; t < nt; ++t) {
    if (t < nt - 1) asm volatile("s_waitcnt vmcnt(4)" ::: "memory");
    else            asm volatile("s_waitcnt vmcnt(0)" ::: "memory");
    __builtin_amdgcn_s_barrier();
    __builtin_amdgcn_sched_barrier(0);
    if (t + 2 < nt) {
      int bn = bcur + 2; if (bn >= 3) bn -= 3;
      stage(bn, kt0 + t + 2);
    }
    const unsigned short* Kb = (const unsigned short*)(smem + (size_t)bcur * 16384);
    const unsigned short* Vb = Kb + 4096;

    /* ---- S^T[64k][32q] x 2 q-sets; each K-frag read feeds 2 MFMAs ---- */
    f32x16 st[2][2];   /* [s2][khalf] */
#pragma unroll
    for (int s2 = 0; s2 < 2; s2++)
#pragma unroll
      for (int r = 0; r < 16; r++) { st[s2][0][r] = 0.f; st[s2][1][r] = 0.f; }
    __builtin_amdgcn_s_setprio(1);
#pragma unroll
    for (int c = 0; c < 4; c++) {
      int ch = (((c << 1) | hi) ^ swq) << 3;
      bf16x8 ak0 = *(const bf16x8*)&Kb[q * 64 + ch];
      bf16x8 ak1 = *(const bf16x8*)&Kb[(32 + q) * 64 + ch];
      st[0][0] = __builtin_amdgcn_mfma_f32_32x32x16_bf16(ak0, bqf[0][c], st[0][0], 0, 0, 0);
      st[0][1] = __builtin_amdgcn_mfma_f32_32x32x16_bf16(ak1, bqf[0][c], st[0][1], 0, 0, 0);
      st[1][0] = __builtin_amdgcn_mfma_f32_32x32x16_bf16(ak0, bqf[1][c], st[1][0], 0, 0, 0);
      st[1][1] = __builtin_amdgcn_mfma_f32_32x32x16_bf16(ak1, bqf[1][c], st[1][1], 0, 0, 0);
    }
    __builtin_amdgcn_s_setprio(0);

    /* ---- P = exp2(S) -> bf16 pairs in regs (no l VALU: ones-MFMA handles it) ---- */
    unsigned int pk[2][2][8];   /* [s2][khalf][pair] */
#pragma unroll
    for (int s2 = 0; s2 < 2; s2++) {
#pragma unroll
      for (int p = 0; p < 8; p++) {
        float e0 = __builtin_amdgcn_exp2f(st[s2][0][2 * p]);
        float e1 = __builtin_amdgcn_exp2f(st[s2][0][2 * p + 1]);
        float e2 = __builtin_amdgcn_exp2f(st[s2][1][2 * p]);
        float e3 = __builtin_amdgcn_exp2f(st[s2][1][2 * p + 1]);
        pk[s2][0][p] = cvtpk_bf16(e0, e1);
        pk[s2][1][p] = cvtpk_bf16(e2, e3);
      }
      plane32_swap(pk[s2][0][0], pk[s2][0][2]); plane32_swap(pk[s2][0][1], pk[s2][0][3]);
      plane32_swap(pk[s2][0][4], pk[s2][0][6]); plane32_swap(pk[s2][0][5], pk[s2][0][7]);
      plane32_swap(pk[s2][1][0], pk[s2][1][2]); plane32_swap(pk[s2][1][1], pk[s2][1][3]);
      plane32_swap(pk[s2][1][4], pk[s2][1][6]); plane32_swap(pk[s2][1][5], pk[s2][1][7]);
    }

    /* ---- O^T += V^T . P^T ; l += ones . P^T (MFMA pipe) ---- */
    __builtin_amdgcn_s_setprio(1);
#pragma unroll
    for (int t4 = 0; t4 < 4; t4++) {              /* j-chunk of 16 */
      int ch = (((t4 << 1) | hi) ^ swq) << 3;
      union { unsigned int u[4]; bf16x8 v; } pb0, pb1;
#pragma unroll
      for (int j = 0; j < 4; j++) {
        pb0.u[j] = pk[0][t4 >> 1][(t4 & 1) * 4 + j];
        pb1.u[j] = pk[1][t4 >> 1][(t4 & 1) * 4 + j];
      }
      o_l[0] = __builtin_amdgcn_mfma_f32_32x32x16_bf16(kOnes, pb0.v, o_l[0], 0, 0, 0);
      o_l[1] = __builtin_amdgcn_mfma_f32_32x32x16_bf16(kOnes, pb1.v, o_l[1], 0, 0, 0);
#pragma unroll
      for (int dt = 0; dt < 2; dt++) {
        bf16x8 av = *(const bf16x8*)&Vb[(dt * 32 + q) * 64 + ch];
        o_acc[0][dt] = __builtin_amdgcn_mfma_f32_32x32x16_bf16(av, pb0.v, o_acc[0][dt], 0, 0, 0);
        o_acc[1][dt] = __builtin_amdgcn_mfma_f32_32x32x16_bf16(av, pb1.v, o_acc[1][dt], 0, 0, 0);
      }
    }
    __builtin_amdgcn_s_setprio(0);
    bcur = (bcur == 2) ? 0 : bcur + 1;
  }

  /* ---- epilogue: write UNNORMALIZED bf16 partial O and f32 l for this split ---- */
  unsigned short* Pp = ws + (size_t)s * SMK;             /* QB/KB/VB region */
  float* lf = (float*)(ws + OFF_WQ);
#pragma unroll
  for (int s2 = 0; s2 < 2; s2++) {
    int srow = qblk * 256 + wsub * 64 + s2 * 32 + q;
    lf[((s * NB + b) * NH + h) * SEQ + srow] = o_l[s2][0];  /* same value in all regs/halves */
    int qg = b * SEQ + srow;
    unsigned short* prow = Pp + (size_t)qg * DM + h * 64;
#pragma unroll
    for (int dt = 0; dt < 2; dt++)
#pragma unroll
      for (int rq = 0; rq < 4; rq++) {
        ushort4 o;
        o.x = f2bf(o_acc[s2][dt][4 * rq + 0]);
        o.y = f2bf(o_acc[s2][dt][4 * rq + 1]);
        o.z = f2bf(o_acc[s2][dt][4 * rq + 2]);
        o.w = f2bf(o_acc[s2][dt][4 * rq + 3]);
        *(ushort4*)&prow[dt * 32 + rq * 8 + hi * 4] = o;
      }
  }
}

/* ---------------- combine the 3 split partials: concat = (P0+P1+P2)/(l0+l1+l2) --------
 * Elementwise, in place over P0 (= concat region). 2048 blocks x 256 thr, 8 elems/thr. */
__global__ __launch_bounds__(256) void combine_splits(unsigned short* ws) {
  int i = blockIdx.x * 256 + threadIdx.x;      /* 0..524287 */
  size_t e0 = (size_t)i * 8;
  int row = (int)(e0 >> 10);                   /* 0..4095 */
  int col = (int)(e0 & 1023);
  int b = row >> 11, srow = row & 2047, h = col >> 6;
  const float* lf = (const float*)(ws + OFF_WQ);
  float l = lf[((0 * NB + b) * NH + h) * SEQ + srow]
          + lf[((1 * NB + b) * NH + h) * SEQ + srow]
          + lf[((2 * NB + b) * NH + h) * SEQ + srow];
  float inv = 1.f / l;
  bf16x8 p0 = *(const bf16x8*)(ws + OFF_QB + e0);
  bf16x8 p1 = *(const bf16x8*)(ws + OFF_KB + e0);
  bf16x8 p2 = *(const bf16x8*)(ws + OFF_VB + e0);
  bf16x8 o;
#pragma unroll
  for (int j = 0; j < 8; j++) {
    float f = (bf2f((unsigned short)p0[j]) + bf2f((unsigned short)p1[j])
             + bf2f((unsigned short)p2[j])) * inv;
    o[j] = (short)f2bf(f);
  }
  *(bf16x8*)(ws + OFF_CC + e0) = o;            /* in place over P0 */
}

/* ---------------- launch ---------------- */
extern "C" void kernel_launch(void* const* d_in, const int* in_sizes, int n_in,
                              void* d_out, int out_size, void* d_ws, size_t ws_size,
                              hipStream_t stream) {
  const float* q  = (const float*)d_in[0];
  const float* k  = (const float*)d_in[1];
  const float* v  = (const float*)d_in[2];
  const float* Wq = (const float*)d_in[3];
  const float* bq = (const float*)d_in[4];
  const float* Wk = (const float*)d_in[5];
  const float* bk = (const float*)d_in[6];
  const float* Wv = (const float*)d_in[7];
  const float* bv = (const float*)d_in[8];
  const float* Wo = (const float*)d_in[9];
  const float* bo = (const float*)d_in[10];

  unsigned short* ws = (unsigned short*)d_ws;
  float* out = (float*)d_out;

  /* converts: 2 z-batched kernels */
  cvt_inputs<<<dim3(SMK / 1024, 3), dim3(256), 0, stream>>>(q, k, v, ws + OFF_QB);
  cvt_weights<<<dim3(W1M / 1024, 4), dim3(256), 0, stream>>>(Wq, Wk, Wv, Wo, ws + OFF_WQ);

  /* Q (prescaled), K, V^T projections: z-batched, 3 x 256 blocks */
  gemm_qkv<<<dim3(256, 1, 3), dim3(256), 0, stream>>>(ws, bq, bk, bv);

  /* attention: 768 independent split-K blocks x 256 threads */
  flash_attn<<<dim3(768), dim3(256), 0, stream>>>(ws);

  /* combine split partials -> concat (in place over split-0 buffer) */
  combine_splits<<<dim3(2048), dim3(256), 0, stream>>>(ws);

  /* output projection -> f32 d_out: 64x128 tiles, 8 x 64 grid */
  gemm_out<<<dim3(DM / 128, MR / 64, 1), dim3(256), 0, stream>>>(ws, bo, out);
}

// Round 9
// 121.069 us; speedup vs baseline: 1.7822x; 1.7822x over previous
//
#include <hip/hip_runtime.h>
#include <hip/hip_bf16.h>

typedef __attribute__((ext_vector_type(8))) short bf16x8;
typedef __attribute__((ext_vector_type(4))) float f32x4;
typedef __attribute__((ext_vector_type(16))) float f32x16;

#define DM   1024
#define SEQ  2048
#define NB   2
#define NH   16
#define MR   (NB*SEQ)            /* 4096 rows of the flattened [B*S, D] matrices */

#define SMK  (MR*DM)             /* 4194304 elements per [4096,1024] tensor */
#define W1M  (DM*DM)             /* 1048576 elements per weight matrix */

/* 0.125 * log2(e): folded into Q projection so attention uses exp2 directly */
#define QSCALE 0.18033688011112042f

/* workspace layout, in bf16 (ushort) units. concat aliases qb (dead after proj GEMM). */
#define OFF_QB  ((size_t)0)
#define OFF_KB  ((size_t)SMK)
#define OFF_VB  ((size_t)(2*(size_t)SMK))
#define OFF_WQ  ((size_t)(3*(size_t)SMK))                       /* WK=+W1M, WV=+2*W1M, WO=+3*W1M */
#define OFF_WO  ((size_t)(3*(size_t)SMK + 3*(size_t)W1M))
#define OFF_QP  ((size_t)(3*(size_t)SMK + 4*(size_t)W1M))
#define OFF_KP  ((size_t)(4*(size_t)SMK + 4*(size_t)W1M))
#define OFF_VP  ((size_t)(5*(size_t)SMK + 4*(size_t)W1M))       /* V^T: [DM][MR] */
#define OFF_CC  ((size_t)0)

__device__ __forceinline__ unsigned short f2bf(float f) {
  union { __hip_bfloat16 b; unsigned short u; } cv;
  cv.b = __float2bfloat16(f);
  return cv.u;
}

/* v_cvt_pk_bf16_f32: packs (lo,hi) floats into one u32 of 2 bf16 */
__device__ __forceinline__ unsigned int cvtpk_bf16(float lo, float hi) {
  unsigned int r;
  asm("v_cvt_pk_bf16_f32 %0, %1, %2" : "=v"(r) : "v"(lo), "v"(hi));
  return r;
}

/* v_permlane32_swap_b32: a.upper32lanes <-> b.lower32lanes (both results used) */
__device__ __forceinline__ void plane32_swap(unsigned int& a, unsigned int& b) {
  asm("v_permlane32_swap_b32 %0, %1" : "+v"(a), "+v"(b));
}

/* ---------------- all f32 -> bf16 converts in ONE kernel ----------------
 * inputs: 3 x SMK elems (q,k,v); weights: 4 x W1M (Wq,Wk,Wv,Wo). 4 elems/thread.
 * All divisors are powers of two -> pure shift arithmetic. */
__global__ __launch_bounds__(256) void cvt_all(const float* __restrict__ q,
                                               const float* __restrict__ k,
                                               const float* __restrict__ v,
                                               const float* __restrict__ wq,
                                               const float* __restrict__ wk,
                                               const float* __restrict__ wv,
                                               const float* __restrict__ wo,
                                               unsigned short* __restrict__ ws) {
  int i = blockIdx.x * 256 + threadIdx.x;
  const float* src;
  unsigned short* dst;
  int j;
  if (i < 3 * (SMK / 4)) {
    int z = i >> 20;                  /* SMK/4 = 2^20 */
    j = i & ((SMK / 4) - 1);
    src = (z == 0) ? q : ((z == 1) ? k : v);
    dst = ws + OFF_QB + (size_t)z * SMK;
  } else {
    int i2 = i - 3 * (SMK / 4);
    int z = i2 >> 18;                 /* W1M/4 = 2^18 */
    j = i2 & ((W1M / 4) - 1);
    src = (z == 0) ? wq : ((z == 1) ? wk : ((z == 2) ? wv : wo));
    dst = ws + OFF_WQ + (size_t)z * W1M;
  }
  float4 val = reinterpret_cast<const float4*>(src)[j];
  ushort4 o;
  o.x = f2bf(val.x); o.y = f2bf(val.y); o.z = f2bf(val.z); o.w = f2bf(val.w);
  reinterpret_cast<ushort4*>(dst)[j] = o;
}

/* ---------------- async global->LDS, 16B per lane ---------------- */
__device__ __forceinline__ void gload_lds16(const void* g, void* l) {
  __builtin_amdgcn_global_load_lds(
      (const __attribute__((address_space(1))) unsigned int*)g,
      (__attribute__((address_space(3))) unsigned int*)l,
      16, 0, 0);
}

/* ---------------- BMxBN tile GEMM body, C = (A * Bt^T + bias) * scale ----------------
 * A: [M][K] bf16 row-major, Bt: [N][K] bf16 row-major (i.e. y = x @ W.T).
 * 4 waves as 2x2, wave tile (BM/2)x(BN/2). 3-buffer LDS, depth-2 prefetch,
 * raw s_barrier + counted vmcnt (never drains to 0 mid-loop). */
template<int BM, int BN, bool OUT_BF16, bool BIAS_ROW>
__device__ __forceinline__ void gemm_bt_body(unsigned short* __restrict__ As,
                                             unsigned short* __restrict__ Bs,
                                             const unsigned short* __restrict__ A,
                                             const unsigned short* __restrict__ Bt,
                                             const float* __restrict__ bias,
                                             void* __restrict__ Cv,
                                             int N, int K, float scale,
                                             int brow, int bcol) {
  constexpr int MREP = BM / 32;
  constexpr int NREP = BN / 32;
  constexpr int LPS  = BM / 64 + BN / 64;   /* gload_lds per wave per stage */
  const int tid  = threadIdx.x;
  const int lane = tid & 63;
  const int w    = tid >> 6;
  const int wr   = w >> 1, wc = w & 1;

  f32x4 acc[MREP][NREP];
#pragma unroll
  for (int m = 0; m < MREP; m++)
#pragma unroll
    for (int n = 0; n < NREP; n++) acc[m][n] = (f32x4){0.f, 0.f, 0.f, 0.f};

  const int srow = lane >> 2;        /* 0..15 row within a 16-row chunk */
  const int scol = (lane & 3) * 8;   /* 0,8,16,24 bf16 col */

  auto stage = [&](int buf, int k0) {
#pragma unroll
    for (int c = w; c < BM / 16; c += 4)
      gload_lds16(A + (size_t)(brow + c * 16 + srow) * K + k0 + scol,
                  (char*)As + (size_t)buf * BM * 64 + c * 1024);
#pragma unroll
    for (int c = w; c < BN / 16; c += 4)
      gload_lds16(Bt + (size_t)(bcol + c * 16 + srow) * K + k0 + scol,
                  (char*)Bs + (size_t)buf * BN * 64 + c * 1024);
  };

  stage(0, 0);
  stage(1, 32);

  const int nk = K / 32;
  const int lrow_a = wr * (BM / 2) + (lane & 15);
  const int lrow_b = wc * (BN / 2) + (lane & 15);
  const int lcol   = (lane >> 4) * 8;

  int b0 = 0;
  for (int kt = 0; kt < nk; ++kt) {
    if (kt + 1 < nk) {
      if constexpr (LPS == 4) asm volatile("s_waitcnt vmcnt(4)" ::: "memory");
      else                    asm volatile("s_waitcnt vmcnt(3)" ::: "memory");
    } else {
      asm volatile("s_waitcnt vmcnt(0)" ::: "memory");
    }
    __builtin_amdgcn_s_barrier();
    __builtin_amdgcn_sched_barrier(0);
    if (kt + 2 < nk) {
      int bn = b0 + 2; if (bn >= 3) bn -= 3;
      stage(bn, (kt + 2) * 32);
    }
    bf16x8 a[MREP], b[NREP];
#pragma unroll
    for (int m = 0; m < MREP; m++)
      a[m] = *(const bf16x8*)&As[(size_t)b0 * BM * 32 + (lrow_a + m * 16) * 32 + lcol];
#pragma unroll
    for (int n = 0; n < NREP; n++)
      b[n] = *(const bf16x8*)&Bs[(size_t)b0 * BN * 32 + (lrow_b + n * 16) * 32 + lcol];
    __builtin_amdgcn_s_setprio(1);
#pragma unroll
    for (int m = 0; m < MREP; m++)
#pragma unroll
      for (int n = 0; n < NREP; n++)
        acc[m][n] = __builtin_amdgcn_mfma_f32_16x16x32_bf16(a[m], b[n], acc[m][n], 0, 0, 0);
    __builtin_amdgcn_s_setprio(0);
    b0 = (b0 == 2) ? 0 : b0 + 1;
  }

  const int crow0 = brow + wr * (BM / 2);
  const int ccol0 = bcol + wc * (BN / 2);
  const int rsub  = (lane >> 4) * 4;
  const int csub  = lane & 15;
#pragma unroll
  for (int m = 0; m < MREP; m++)
#pragma unroll
    for (int n = 0; n < NREP; n++) {
      int col = ccol0 + n * 16 + csub;
      float bcol_v = BIAS_ROW ? 0.f : bias[col];
#pragma unroll
      for (int qq = 0; qq < 4; qq++) {
        int row = crow0 + m * 16 + rsub + qq;
        float bb = BIAS_ROW ? bias[row] : bcol_v;
        float v = (acc[m][n][qq] + bb) * scale;
        if (OUT_BF16)
          ((unsigned short*)Cv)[(size_t)row * N + col] = f2bf(v);
        else
          ((float*)Cv)[(size_t)row * N + col] = v;
      }
    }
}

/* Q (prescaled by QSCALE), K, and V^T projections, z-batched: 768 blocks = 3/CU. */
__global__ __launch_bounds__(256) void gemm_qkv(unsigned short* ws,
                                                const float* __restrict__ bq,
                                                const float* __restrict__ bk,
                                                const float* __restrict__ bv) {
  __shared__ unsigned short As[3 * 128 * 32];
  __shared__ unsigned short Bs[3 * 128 * 32];
  const int z = blockIdx.z;
  const int bid = blockIdx.x;
  if (z < 2) {
    /* [MR][DM] = [MR][DM] @ W^T : grid 8 x 32 */
    int bx = bid & 7, by = bid >> 3;
    gemm_bt_body<128, 128, true, false>(
        As, Bs,
        ws + OFF_QB + (size_t)z * SMK, ws + OFF_WQ + (size_t)z * W1M,
        z ? bk : bq, ws + OFF_QP + (size_t)z * SMK,
        DM, DM, z ? 1.f : QSCALE, by * 128, bx * 128);
  } else {
    /* V^T [DM][MR] = Wv @ v^T : grid 32 x 8, bias per row */
    int bx = bid & 31, by = bid >> 5;
    gemm_bt_body<128, 128, true, true>(
        As, Bs,
        ws + OFF_WQ + 2 * W1M, ws + OFF_VB,
        bv, ws + OFF_VP,
        MR, DM, 1.f, by * 128, bx * 128);
  }
}

/* Output projection: 64x128 tile -> 512 blocks, 36KB LDS. */
__global__ __launch_bounds__(256) void gemm_out(const unsigned short* __restrict__ ws,
                                                const float* __restrict__ bo,
                                                float* __restrict__ out) {
  __shared__ unsigned short As[3 * 64 * 32];
  __shared__ unsigned short Bs[3 * 128 * 32];
  gemm_bt_body<64, 128, false, false>(
      As, Bs,
      ws + OFF_CC, ws + OFF_WO, bo, out,
      DM, DM, 1.f, blockIdx.y * 64, blockIdx.x * 128);
}

/* ---------------- flash attention (R6 structure: split-K x2 in-block) ----------------
 * grid: 512 flat (XCD-swizzled). block: 512 = 8 waves in 2 groups of 4.
 * Group A (w<4): k-tiles 0..15; group B (w>=4): k-tiles 16..31, each group with its
 * own double-buffered K/V LDS stream (4 x 16 KB = 64 KB -> 2 blocks/CU, 4 waves/SIMD).
 * Wave owns 32 q-rows (q = lane&31, hi = lane>>5). S^T/O^T via 32x32x16 MFMA; P stays
 * in registers via v_cvt_pk_bf16_f32 + v_permlane32_swap_b32. No-max softmax
 * (P = exp2(s), shift-invariant, hard-bounded scores) -> split combine is exact;
 * group B spills (O,l) to LDS scratch, group A adds and writes concat. */
__global__ __launch_bounds__(512, 4) void flash_attn(unsigned short* ws) {
  __shared__ __align__(16) unsigned char smem[65536];   /* 4 x (K 8KB | V 8KB) + f32 scratch */

  const int tid  = threadIdx.x;
  const int lane = tid & 63;
  const int w    = tid >> 6;        /* 0..7 */
  const int s    = w >> 2;          /* k-split group: 0 or 1 */
  const int wsub = w & 3;           /* wave within group -> q-subtile */
  const int q    = lane & 31;
  const int hi   = lane >> 5;
  const int swq  = q & 7;
  const int bid  = blockIdx.x;      /* 0..511 */
  const int swzb = (bid & 7) * 64 + (bid >> 3);   /* XCD-contiguous remap */
  const int qblk = swzb & 15;       /* 0..15, 128 q-rows each */
  const int bh   = swzb >> 4;       /* 0..31 */
  const int b    = bh >> 4, h = bh & 15;

  const unsigned short* Qp = ws + OFF_QP;
  const unsigned short* Kp = ws + OFF_KP;
  const unsigned short* Vp = ws + OFF_VP;
  unsigned short* CC = ws + OFF_CC;

  const unsigned short* Kg = Kp + (size_t)(b * SEQ) * DM + h * 64;          /* +row*DM */
  const unsigned short* Vg = Vp + (size_t)(h * 64) * MR + (size_t)b * SEQ;  /* +row*MR */

  /* Q B-fragments (col=q, k=hi*8+i within 16-d chunk c), prescaled by QSCALE */
  bf16x8 bqf[4];
  {
    const unsigned short* qrow =
        Qp + (size_t)(b * SEQ + qblk * 128 + wsub * 32 + q) * DM + h * 64;
#pragma unroll
    for (int c = 0; c < 4; c++)
      bqf[c] = *(const bf16x8*)(qrow + c * 16 + hi * 8);
  }

  f32x16 o_acc[2];
#pragma unroll
  for (int dt = 0; dt < 2; dt++)
#pragma unroll
    for (int r = 0; r < 16; r++) o_acc[dt][r] = 0.f;
  float l_run = 0.f;

  /* stage k-tile (s*16 + t) into this group's buffer `buf`; 4 waves of the group split it */
  auto stage = [&](int buf, int t) {
    const unsigned short* Kt = Kg + (size_t)(s * 16 + t) * 64 * DM;
    const unsigned short* Vt = Vg + (s * 16 + t) * 64;
    char* base = (char*)smem + (size_t)(s * 2 + buf) * 16384;
#pragma unroll
    for (int i = 0; i < 2; i++) {
      int slot = wsub * 128 + i * 64 + lane;   /* 16B slot 0..511 */
      int srow = slot >> 3;                    /* 0..63 */
      int gch  = (slot & 7) ^ (srow & 7);      /* inverse swizzle on global source */
      gload_lds16(Kt + (size_t)srow * DM + gch * 8, base + slot * 16);
      gload_lds16(Vt + (size_t)srow * MR + gch * 8, base + 8192 + slot * 16);
    }
  };

  stage(0, 0);

  for (int t = 0; t < 16; ++t) {
    int buf = t & 1;
    __syncthreads();   /* stage(t) drained (own-wave vmcnt) + all waves arrived */
    if (t + 1 < 16) stage(buf ^ 1, t + 1);
    const unsigned short* Kb = (const unsigned short*)(smem + (size_t)(s * 2 + buf) * 16384);
    const unsigned short* Vb = Kb + 4096;

    /* ---- S^T[64k][32q] = K · Q^T (log2-domain) ---- */
    f32x16 st0, st1;
#pragma unroll
    for (int r = 0; r < 16; r++) { st0[r] = 0.f; st1[r] = 0.f; }
    __builtin_amdgcn_s_setprio(1);
#pragma unroll
    for (int c = 0; c < 4; c++) {
      int ch = (((c << 1) | hi) ^ swq) << 3;
      bf16x8 ak0 = *(const bf16x8*)&Kb[q * 64 + ch];
      bf16x8 ak1 = *(const bf16x8*)&Kb[(32 + q) * 64 + ch];
      st0 = __builtin_amdgcn_mfma_f32_32x32x16_bf16(ak0, bqf[c], st0, 0, 0, 0);
      st1 = __builtin_amdgcn_mfma_f32_32x32x16_bf16(ak1, bqf[c], st1, 0, 0, 0);
    }
    __builtin_amdgcn_s_setprio(0);

    /* ---- P = exp2(S), packed to bf16 pairs; l accumulates in f32 ---- */
    unsigned int pk0[8], pk1[8];
    float lt = 0.f;
#pragma unroll
    for (int p = 0; p < 8; p++) {
      float a0 = __builtin_amdgcn_exp2f(st0[2 * p]);
      float a1 = __builtin_amdgcn_exp2f(st0[2 * p + 1]);
      float b0 = __builtin_amdgcn_exp2f(st1[2 * p]);
      float b1 = __builtin_amdgcn_exp2f(st1[2 * p + 1]);
      lt += (a0 + a1) + (b0 + b1);
      pk0[p] = cvtpk_bf16(a0, a1);
      pk1[p] = cvtpk_bf16(b0, b1);
    }
    l_run += lt;

    /* ---- redistribute hi-halves: pk[0..3] / pk[4..7] become PV B-frags ---- */
    plane32_swap(pk0[0], pk0[2]); plane32_swap(pk0[1], pk0[3]);
    plane32_swap(pk0[4], pk0[6]); plane32_swap(pk0[5], pk0[7]);
    plane32_swap(pk1[0], pk1[2]); plane32_swap(pk1[1], pk1[3]);
    plane32_swap(pk1[4], pk1[6]); plane32_swap(pk1[5], pk1[7]);

    /* ---- O^T[64d][32q] += V^T · P^T ---- */
    __builtin_amdgcn_s_setprio(1);
#pragma unroll
    for (int t4 = 0; t4 < 4; t4++) {              /* j-chunk of 16 */
      union { unsigned int u[4]; bf16x8 v; } pb;
      const unsigned int* src = (t4 < 2) ? pk0 : pk1;
      pb.u[0] = src[(t4 & 1) * 4 + 0];
      pb.u[1] = src[(t4 & 1) * 4 + 1];
      pb.u[2] = src[(t4 & 1) * 4 + 2];
      pb.u[3] = src[(t4 & 1) * 4 + 3];
      int ch = (((t4 << 1) | hi) ^ swq) << 3;
#pragma unroll
      for (int dt = 0; dt < 2; dt++) {
        bf16x8 av = *(const bf16x8*)&Vb[(dt * 32 + q) * 64 + ch];
        o_acc[dt] = __builtin_amdgcn_mfma_f32_32x32x16_bf16(av, pb.v, o_acc[dt], 0, 0, 0);
      }
    }
    __builtin_amdgcn_s_setprio(0);
  }

  /* ---- combine the two k-splits via LDS scratch (staging buffers are dead) ---- */
  __syncthreads();
  float* scr = (float*)smem;
  float lsum = l_run + __shfl_xor(l_run, 32, 64);   /* combine hi halves */
  if (s == 1) {
    int idx = (wsub * 64 + lane) * 33;              /* stride 33: conflict-free */
#pragma unroll
    for (int dt = 0; dt < 2; dt++)
#pragma unroll
      for (int r = 0; r < 16; r++) scr[idx + dt * 16 + r] = o_acc[dt][r];
    scr[idx + 32] = lsum;
  }
  __syncthreads();
  if (s == 0) {
    int idx = (wsub * 64 + lane) * 33;
#pragma unroll
    for (int dt = 0; dt < 2; dt++)
#pragma unroll
      for (int r = 0; r < 16; r++) o_acc[dt][r] += scr[idx + dt * 16 + r];
    float l = lsum + scr[idx + 32];
    float inv = 1.f / l;

    /* ---- epilogue: O^T[d][q], d = dt*32 + 8*(reg>>2) + 4*hi + (reg&3) ---- */
    int qg = b * SEQ + qblk * 128 + wsub * 32 + q;
    unsigned short* crow = CC + (size_t)qg * DM + h * 64;
#pragma unroll
    for (int dt = 0; dt < 2; dt++)
#pragma unroll
      for (int rq = 0; rq < 4; rq++) {
        ushort4 o;
        o.x = f2bf(o_acc[dt][4 * rq + 0] * inv);
        o.y = f2bf(o_acc[dt][4 * rq + 1] * inv);
        o.z = f2bf(o_acc[dt][4 * rq + 2] * inv);
        o.w = f2bf(o_acc[dt][4 * rq + 3] * inv);
        *(ushort4*)&crow[dt * 32 + rq * 8 + hi * 4] = o;
      }
  }
}

/* ---------------- launch ---------------- */
extern "C" void kernel_launch(void* const* d_in, const int* in_sizes, int n_in,
                              void* d_out, int out_size, void* d_ws, size_t ws_size,
                              hipStream_t stream) {
  const float* q  = (const float*)d_in[0];
  const float* k  = (const float*)d_in[1];
  const float* v  = (const float*)d_in[2];
  const float* Wq = (const float*)d_in[3];
  const float* bq = (const float*)d_in[4];
  const float* Wk = (const float*)d_in[5];
  const float* bk = (const float*)d_in[6];
  const float* Wv = (const float*)d_in[7];
  const float* bv = (const float*)d_in[8];
  const float* Wo = (const float*)d_in[9];
  const float* bo = (const float*)d_in[10];

  unsigned short* ws = (unsigned short*)d_ws;
  float* out = (float*)d_out;

  /* all converts in one launch: 3*SMK/4 + 4*W1M/4 threads / 256 */
  cvt_all<<<dim3((3 * (SMK / 4) + 4 * (W1M / 4)) / 256), dim3(256), 0, stream>>>(
      q, k, v, Wq, Wk, Wv, Wo, ws);

  /* Q (prescaled), K, V^T projections: z-batched, 3 x 256 blocks */
  gemm_qkv<<<dim3(256, 1, 3), dim3(256), 0, stream>>>(ws, bq, bk, bv);

  /* attention: 512 blocks x 512 threads, split-K x2 in-block */
  flash_attn<<<dim3(512), dim3(512), 0, stream>>>(ws);

  /* output projection -> f32 d_out: 64x128 tiles, 8 x 64 grid */
  gemm_out<<<dim3(DM / 128, MR / 64, 1), dim3(256), 0, stream>>>(ws, bo, out);
}

// Round 10
// 117.544 us; speedup vs baseline: 1.8356x; 1.0300x over previous
//
#include <hip/hip_runtime.h>
#include <hip/hip_bf16.h>

typedef __attribute__((ext_vector_type(8))) short bf16x8;
typedef __attribute__((ext_vector_type(4))) float f32x4;
typedef __attribute__((ext_vector_type(16))) float f32x16;

#define DM   1024
#define SEQ  2048
#define NB   2
#define NH   16
#define MR   (NB*SEQ)            /* 4096 rows of the flattened [B*S, D] matrices */

#define SMK  (MR*DM)             /* 4194304 elements per [4096,1024] tensor */
#define W1M  (DM*DM)             /* 1048576 elements per weight matrix */

/* 0.125 * log2(e): folded into Q projection so attention uses exp2 directly */
#define QSCALE 0.18033688011112042f

/* workspace layout, in bf16 (ushort) units. concat aliases qb (dead after proj GEMM). */
#define OFF_QB  ((size_t)0)
#define OFF_KB  ((size_t)SMK)
#define OFF_VB  ((size_t)(2*(size_t)SMK))
#define OFF_WQ  ((size_t)(3*(size_t)SMK))                       /* WK=+W1M, WV=+2*W1M, WO=+3*W1M */
#define OFF_WO  ((size_t)(3*(size_t)SMK + 3*(size_t)W1M))
#define OFF_QP  ((size_t)(3*(size_t)SMK + 4*(size_t)W1M))
#define OFF_KP  ((size_t)(4*(size_t)SMK + 4*(size_t)W1M))
#define OFF_VP  ((size_t)(5*(size_t)SMK + 4*(size_t)W1M))       /* V^T: [DM][MR] */
#define OFF_CC  ((size_t)0)

__device__ __forceinline__ unsigned short f2bf(float f) {
  union { __hip_bfloat16 b; unsigned short u; } cv;
  cv.b = __float2bfloat16(f);
  return cv.u;
}

/* v_cvt_pk_bf16_f32: packs (lo,hi) floats into one u32 of 2 bf16 */
__device__ __forceinline__ unsigned int cvtpk_bf16(float lo, float hi) {
  unsigned int r;
  asm("v_cvt_pk_bf16_f32 %0, %1, %2" : "=v"(r) : "v"(lo), "v"(hi));
  return r;
}

/* v_permlane32_swap_b32: a.upper32lanes <-> b.lower32lanes (both results used) */
__device__ __forceinline__ void plane32_swap(unsigned int& a, unsigned int& b) {
  asm("v_permlane32_swap_b32 %0, %1" : "+v"(a), "+v"(b));
}

/* ---------------- all f32 -> bf16 converts in ONE kernel ---------------- */
__global__ __launch_bounds__(256) void cvt_all(const float* __restrict__ q,
                                               const float* __restrict__ k,
                                               const float* __restrict__ v,
                                               const float* __restrict__ wq,
                                               const float* __restrict__ wk,
                                               const float* __restrict__ wv,
                                               const float* __restrict__ wo,
                                               unsigned short* __restrict__ ws) {
  int i = blockIdx.x * 256 + threadIdx.x;
  const float* src;
  unsigned short* dst;
  int j;
  if (i < 3 * (SMK / 4)) {
    int z = i >> 20;                  /* SMK/4 = 2^20 */
    j = i & ((SMK / 4) - 1);
    src = (z == 0) ? q : ((z == 1) ? k : v);
    dst = ws + OFF_QB + (size_t)z * SMK;
  } else {
    int i2 = i - 3 * (SMK / 4);
    int z = i2 >> 18;                 /* W1M/4 = 2^18 */
    j = i2 & ((W1M / 4) - 1);
    src = (z == 0) ? wq : ((z == 1) ? wk : ((z == 2) ? wv : wo));
    dst = ws + OFF_WQ + (size_t)z * W1M;
  }
  float4 val = reinterpret_cast<const float4*>(src)[j];
  ushort4 o;
  o.x = f2bf(val.x); o.y = f2bf(val.y); o.z = f2bf(val.z); o.w = f2bf(val.w);
  reinterpret_cast<ushort4*>(dst)[j] = o;
}

/* ---------------- async global->LDS, 16B per lane ---------------- */
__device__ __forceinline__ void gload_lds16(const void* g, void* l) {
  __builtin_amdgcn_global_load_lds(
      (const __attribute__((address_space(1))) unsigned int*)g,
      (__attribute__((address_space(3))) unsigned int*)l,
      16, 0, 0);
}

/* ---------------- BMxBN tile GEMM body, C = (A * Bt^T + bias) * scale ----------------
 * A: [M][K] bf16 row-major, Bt: [N][K] bf16 row-major (i.e. y = x @ W.T).
 * 4 waves as 2x2, wave tile (BM/2)x(BN/2). 3-buffer LDS, depth-2 prefetch,
 * raw s_barrier + counted vmcnt (never drains to 0 mid-loop). */
template<int BM, int BN, bool OUT_BF16, bool BIAS_ROW>
__device__ __forceinline__ void gemm_bt_body(unsigned short* __restrict__ As,
                                             unsigned short* __restrict__ Bs,
                                             const unsigned short* __restrict__ A,
                                             const unsigned short* __restrict__ Bt,
                                             const float* __restrict__ bias,
                                             void* __restrict__ Cv,
                                             int N, int K, float scale,
                                             int brow, int bcol) {
  constexpr int MREP = BM / 32;
  constexpr int NREP = BN / 32;
  constexpr int LPS  = BM / 64 + BN / 64;   /* gload_lds per wave per stage */
  const int tid  = threadIdx.x;
  const int lane = tid & 63;
  const int w    = tid >> 6;
  const int wr   = w >> 1, wc = w & 1;

  f32x4 acc[MREP][NREP];
#pragma unroll
  for (int m = 0; m < MREP; m++)
#pragma unroll
    for (int n = 0; n < NREP; n++) acc[m][n] = (f32x4){0.f, 0.f, 0.f, 0.f};

  const int srow = lane >> 2;        /* 0..15 row within a 16-row chunk */
  const int scol = (lane & 3) * 8;   /* 0,8,16,24 bf16 col */

  auto stage = [&](int buf, int k0) {
#pragma unroll
    for (int c = w; c < BM / 16; c += 4)
      gload_lds16(A + (size_t)(brow + c * 16 + srow) * K + k0 + scol,
                  (char*)As + (size_t)buf * BM * 64 + c * 1024);
#pragma unroll
    for (int c = w; c < BN / 16; c += 4)
      gload_lds16(Bt + (size_t)(bcol + c * 16 + srow) * K + k0 + scol,
                  (char*)Bs + (size_t)buf * BN * 64 + c * 1024);
  };

  stage(0, 0);
  stage(1, 32);

  const int nk = K / 32;
  const int lrow_a = wr * (BM / 2) + (lane & 15);
  const int lrow_b = wc * (BN / 2) + (lane & 15);
  const int lcol   = (lane >> 4) * 8;

  int b0 = 0;
  for (int kt = 0; kt < nk; ++kt) {
    if (kt + 1 < nk) {
      if constexpr (LPS == 4) asm volatile("s_waitcnt vmcnt(4)" ::: "memory");
      else                    asm volatile("s_waitcnt vmcnt(3)" ::: "memory");
    } else {
      asm volatile("s_waitcnt vmcnt(0)" ::: "memory");
    }
    __builtin_amdgcn_s_barrier();
    __builtin_amdgcn_sched_barrier(0);
    if (kt + 2 < nk) {
      int bn = b0 + 2; if (bn >= 3) bn -= 3;
      stage(bn, (kt + 2) * 32);
    }
    bf16x8 a[MREP], b[NREP];
#pragma unroll
    for (int m = 0; m < MREP; m++)
      a[m] = *(const bf16x8*)&As[(size_t)b0 * BM * 32 + (lrow_a + m * 16) * 32 + lcol];
#pragma unroll
    for (int n = 0; n < NREP; n++)
      b[n] = *(const bf16x8*)&Bs[(size_t)b0 * BN * 32 + (lrow_b + n * 16) * 32 + lcol];
    __builtin_amdgcn_s_setprio(1);
#pragma unroll
    for (int m = 0; m < MREP; m++)
#pragma unroll
      for (int n = 0; n < NREP; n++)
        acc[m][n] = __builtin_amdgcn_mfma_f32_16x16x32_bf16(a[m], b[n], acc[m][n], 0, 0, 0);
    __builtin_amdgcn_s_setprio(0);
    b0 = (b0 == 2) ? 0 : b0 + 1;
  }

  const int crow0 = brow + wr * (BM / 2);
  const int ccol0 = bcol + wc * (BN / 2);
  const int rsub  = (lane >> 4) * 4;
  const int csub  = lane & 15;
#pragma unroll
  for (int m = 0; m < MREP; m++)
#pragma unroll
    for (int n = 0; n < NREP; n++) {
      int col = ccol0 + n * 16 + csub;
      float bcol_v = BIAS_ROW ? 0.f : bias[col];
#pragma unroll
      for (int qq = 0; qq < 4; qq++) {
        int row = crow0 + m * 16 + rsub + qq;
        float bb = BIAS_ROW ? bias[row] : bcol_v;
        float v = (acc[m][n][qq] + bb) * scale;
        if (OUT_BF16)
          ((unsigned short*)Cv)[(size_t)row * N + col] = f2bf(v);
        else
          ((float*)Cv)[(size_t)row * N + col] = v;
      }
    }
}

/* Q (prescaled by QSCALE), K, V^T projections. Flat 768-block grid with
 * panel-colocating XCD swizzle: the 8 blocks sharing an operand panel get
 * indices == x (mod 8) at consecutive slots -> same XCD, co-resident ->
 * panel served from that XCD's L2 after first touch. */
__global__ __launch_bounds__(256) void gemm_qkv(unsigned short* ws,
                                                const float* __restrict__ bq,
                                                const float* __restrict__ bk,
                                                const float* __restrict__ bv) {
  __shared__ unsigned short As[3 * 128 * 32];
  __shared__ unsigned short Bs[3 * 128 * 32];
  const int i  = blockIdx.x;        /* 0..767 */
  const int x  = i & 7;             /* target XCD (dispatch round-robin) */
  const int r  = i >> 3;            /* 0..95: slot within XCD */
  const int pm = r >> 3;            /* 0..11 */
  const int bx = r & 7;             /* 0..7: position within panel-group */
  const int p  = x * 12 + pm;       /* 0..95: panel-group id */
  const int z  = p >> 5;            /* 0..2 */
  const int by = p & 31;            /* 0..31: panel index */
  if (z < 2) {
    /* [MR][DM] = x_z @ W_z^T; panel = 128 input rows (shared by bx=0..7) */
    gemm_bt_body<128, 128, true, false>(
        As, Bs,
        ws + OFF_QB + (size_t)z * SMK, ws + OFF_WQ + (size_t)z * W1M,
        z ? bk : bq, ws + OFF_QP + (size_t)z * SMK,
        DM, DM, z ? 1.f : QSCALE, by * 128, bx * 128);
  } else {
    /* V^T [DM][MR] = Wv @ v^T; panel = 128 v rows (Bt side, shared by bx) */
    gemm_bt_body<128, 128, true, true>(
        As, Bs,
        ws + OFF_WQ + 2 * W1M, ws + OFF_VB,
        bv, ws + OFF_VP,
        MR, DM, 1.f, bx * 128, by * 128);
  }
}

/* Output projection: 512 blocks, same panel-colocating swizzle (64-row panels). */
__global__ __launch_bounds__(256) void gemm_out(const unsigned short* __restrict__ ws,
                                                const float* __restrict__ bo,
                                                float* __restrict__ out) {
  __shared__ unsigned short As[3 * 64 * 32];
  __shared__ unsigned short Bs[3 * 128 * 32];
  const int i  = blockIdx.x;        /* 0..511 */
  const int x  = i & 7;
  const int r  = i >> 3;            /* 0..63 */
  const int pm = r >> 3;            /* 0..7 */
  const int bx = r & 7;
  const int by = x * 8 + pm;        /* 0..63 */
  gemm_bt_body<64, 128, false, false>(
      As, Bs,
      ws + OFF_CC, ws + OFF_WO, bo, out,
      DM, DM, 1.f, by * 64, bx * 128);
}

/* ---------------- flash attention (R6/R9 structure + ones-MFMA l) ----------------
 * grid: 512 flat (XCD-swizzled). block: 512 = 8 waves in 2 split-K groups of 4.
 * Wave owns 32 q-rows (q = lane&31). S^T/O^T via 32x32x16 MFMA; P in registers via
 * cvt_pk + permlane32_swap. l computed by ones-MFMA (every o_l reg = l_q exactly) —
 * no VALU adds, no shuffles. No-max softmax keeps split-K combine exact. */
__global__ __launch_bounds__(512, 4) void flash_attn(unsigned short* ws) {
  __shared__ __align__(16) unsigned char smem[65536];   /* 4 x (K 8KB | V 8KB) + f32 scratch */

  const int tid  = threadIdx.x;
  const int lane = tid & 63;
  const int w    = tid >> 6;        /* 0..7 */
  const int s    = w >> 2;          /* k-split group: 0 or 1 */
  const int wsub = w & 3;           /* wave within group -> q-subtile */
  const int q    = lane & 31;
  const int hi   = lane >> 5;
  const int swq  = q & 7;
  const int bid  = blockIdx.x;      /* 0..511 */
  const int swzb = (bid & 7) * 64 + (bid >> 3);   /* XCD-contiguous remap */
  const int qblk = swzb & 15;       /* 0..15, 128 q-rows each */
  const int bh   = swzb >> 4;       /* 0..31 */
  const int b    = bh >> 4, h = bh & 15;

  const unsigned short* Qp = ws + OFF_QP;
  const unsigned short* Kp = ws + OFF_KP;
  const unsigned short* Vp = ws + OFF_VP;
  unsigned short* CC = ws + OFF_CC;

  const unsigned short* Kg = Kp + (size_t)(b * SEQ) * DM + h * 64;          /* +row*DM */
  const unsigned short* Vg = Vp + (size_t)(h * 64) * MR + (size_t)b * SEQ;  /* +row*MR */

  /* Q B-fragments (col=q, k=hi*8+i within 16-d chunk c), prescaled by QSCALE */
  bf16x8 bqf[4];
  {
    const unsigned short* qrow =
        Qp + (size_t)(b * SEQ + qblk * 128 + wsub * 32 + q) * DM + h * 64;
#pragma unroll
    for (int c = 0; c < 4; c++)
      bqf[c] = *(const bf16x8*)(qrow + c * 16 + hi * 8);
  }

  const bf16x8 kOnes = {16256, 16256, 16256, 16256, 16256, 16256, 16256, 16256}; /* bf16 1.0 */

  f32x16 o_acc[2];
  f32x16 o_l;
#pragma unroll
  for (int r = 0; r < 16; r++) o_l[r] = 0.f;
#pragma unroll
  for (int dt = 0; dt < 2; dt++)
#pragma unroll
    for (int r = 0; r < 16; r++) o_acc[dt][r] = 0.f;

  /* stage k-tile (s*16 + t) into this group's buffer `buf`; 4 waves of the group split it */
  auto stage = [&](int buf, int t) {
    const unsigned short* Kt = Kg + (size_t)(s * 16 + t) * 64 * DM;
    const unsigned short* Vt = Vg + (s * 16 + t) * 64;
    char* base = (char*)smem + (size_t)(s * 2 + buf) * 16384;
#pragma unroll
    for (int i = 0; i < 2; i++) {
      int slot = wsub * 128 + i * 64 + lane;   /* 16B slot 0..511 */
      int srow = slot >> 3;                    /* 0..63 */
      int gch  = (slot & 7) ^ (srow & 7);      /* inverse swizzle on global source */
      gload_lds16(Kt + (size_t)srow * DM + gch * 8, base + slot * 16);
      gload_lds16(Vt + (size_t)srow * MR + gch * 8, base + 8192 + slot * 16);
    }
  };

  stage(0, 0);

  for (int t = 0; t < 16; ++t) {
    int buf = t & 1;
    __syncthreads();   /* stage(t) drained (own-wave vmcnt) + all waves arrived */
    if (t + 1 < 16) stage(buf ^ 1, t + 1);
    const unsigned short* Kb = (const unsigned short*)(smem + (size_t)(s * 2 + buf) * 16384);
    const unsigned short* Vb = Kb + 4096;

    /* ---- S^T[64k][32q] = K · Q^T (log2-domain) ---- */
    f32x16 st0, st1;
#pragma unroll
    for (int r = 0; r < 16; r++) { st0[r] = 0.f; st1[r] = 0.f; }
    __builtin_amdgcn_s_setprio(1);
#pragma unroll
    for (int c = 0; c < 4; c++) {
      int ch = (((c << 1) | hi) ^ swq) << 3;
      bf16x8 ak0 = *(const bf16x8*)&Kb[q * 64 + ch];
      bf16x8 ak1 = *(const bf16x8*)&Kb[(32 + q) * 64 + ch];
      st0 = __builtin_amdgcn_mfma_f32_32x32x16_bf16(ak0, bqf[c], st0, 0, 0, 0);
      st1 = __builtin_amdgcn_mfma_f32_32x32x16_bf16(ak1, bqf[c], st1, 0, 0, 0);
    }
    __builtin_amdgcn_s_setprio(0);

    /* ---- P = exp2(S), packed to bf16 pairs (no l VALU: ones-MFMA handles it) ---- */
    unsigned int pk0[8], pk1[8];
#pragma unroll
    for (int p = 0; p < 8; p++) {
      float a0 = __builtin_amdgcn_exp2f(st0[2 * p]);
      float a1 = __builtin_amdgcn_exp2f(st0[2 * p + 1]);
      float b0 = __builtin_amdgcn_exp2f(st1[2 * p]);
      float b1 = __builtin_amdgcn_exp2f(st1[2 * p + 1]);
      pk0[p] = cvtpk_bf16(a0, a1);
      pk1[p] = cvtpk_bf16(b0, b1);
    }

    /* ---- redistribute hi-halves: pk[0..3] / pk[4..7] become PV B-frags ---- */
    plane32_swap(pk0[0], pk0[2]); plane32_swap(pk0[1], pk0[3]);
    plane32_swap(pk0[4], pk0[6]); plane32_swap(pk0[5], pk0[7]);
    plane32_swap(pk1[0], pk1[2]); plane32_swap(pk1[1], pk1[3]);
    plane32_swap(pk1[4], pk1[6]); plane32_swap(pk1[5], pk1[7]);

    /* ---- O^T[64d][32q] += V^T · P^T ; l[q] += ones · P^T (MFMA pipe) ---- */
    __builtin_amdgcn_s_setprio(1);
#pragma unroll
    for (int t4 = 0; t4 < 4; t4++) {              /* j-chunk of 16 */
      union { unsigned int u[4]; bf16x8 v; } pb;
      const unsigned int* src = (t4 < 2) ? pk0 : pk1;
      pb.u[0] = src[(t4 & 1) * 4 + 0];
      pb.u[1] = src[(t4 & 1) * 4 + 1];
      pb.u[2] = src[(t4 & 1) * 4 + 2];
      pb.u[3] = src[(t4 & 1) * 4 + 3];
      int ch = (((t4 << 1) | hi) ^ swq) << 3;
      o_l = __builtin_amdgcn_mfma_f32_32x32x16_bf16(kOnes, pb.v, o_l, 0, 0, 0);
#pragma unroll
      for (int dt = 0; dt < 2; dt++) {
        bf16x8 av = *(const bf16x8*)&Vb[(dt * 32 + q) * 64 + ch];
        o_acc[dt] = __builtin_amdgcn_mfma_f32_32x32x16_bf16(av, pb.v, o_acc[dt], 0, 0, 0);
      }
    }
    __builtin_amdgcn_s_setprio(0);
  }

  /* ---- combine the two k-splits via LDS scratch (staging buffers are dead) ---- */
  __syncthreads();
  float* scr = (float*)smem;
  float lsum = o_l[0];              /* ones-MFMA: every reg (both hi halves) = l_q */
  if (s == 1) {
    int idx = (wsub * 64 + lane) * 33;              /* stride 33: conflict-free */
#pragma unroll
    for (int dt = 0; dt < 2; dt++)
#pragma unroll
      for (int r = 0; r < 16; r++) scr[idx + dt * 16 + r] = o_acc[dt][r];
    scr[idx + 32] = lsum;
  }
  __syncthreads();
  if (s == 0) {
    int idx = (wsub * 64 + lane) * 33;
#pragma unroll
    for (int dt = 0; dt < 2; dt++)
#pragma unroll
      for (int r = 0; r < 16; r++) o_acc[dt][r] += scr[idx + dt * 16 + r];
    float l = lsum + scr[idx + 32];
    float inv = 1.f / l;

    /* ---- epilogue: O^T[d][q], d = dt*32 + 8*(reg>>2) + 4*hi + (reg&3) ---- */
    int qg = b * SEQ + qblk * 128 + wsub * 32 + q;
    unsigned short* crow = CC + (size_t)qg * DM + h * 64;
#pragma unroll
    for (int dt = 0; dt < 2; dt++)
#pragma unroll
      for (int rq = 0; rq < 4; rq++) {
        ushort4 o;
        o.x = f2bf(o_acc[dt][4 * rq + 0] * inv);
        o.y = f2bf(o_acc[dt][4 * rq + 1] * inv);
        o.z = f2bf(o_acc[dt][4 * rq + 2] * inv);
        o.w = f2bf(o_acc[dt][4 * rq + 3] * inv);
        *(ushort4*)&crow[dt * 32 + rq * 8 + hi * 4] = o;
      }
  }
}

/* ---------------- launch ---------------- */
extern "C" void kernel_launch(void* const* d_in, const int* in_sizes, int n_in,
                              void* d_out, int out_size, void* d_ws, size_t ws_size,
                              hipStream_t stream) {
  const float* q  = (const float*)d_in[0];
  const float* k  = (const float*)d_in[1];
  const float* v  = (const float*)d_in[2];
  const float* Wq = (const float*)d_in[3];
  const float* bq = (const float*)d_in[4];
  const float* Wk = (const float*)d_in[5];
  const float* bk = (const float*)d_in[6];
  const float* Wv = (const float*)d_in[7];
  const float* bv = (const float*)d_in[8];
  const float* Wo = (const float*)d_in[9];
  const float* bo = (const float*)d_in[10];

  unsigned short* ws = (unsigned short*)d_ws;
  float* out = (float*)d_out;

  /* all converts in one launch: 3*SMK/4 + 4*W1M/4 threads / 256 */
  cvt_all<<<dim3((3 * (SMK / 4) + 4 * (W1M / 4)) / 256), dim3(256), 0, stream>>>(
      q, k, v, Wq, Wk, Wv, Wo, ws);

  /* Q (prescaled), K, V^T projections: flat 768 blocks, panel-colocating swizzle */
  gemm_qkv<<<dim3(768), dim3(256), 0, stream>>>(ws, bq, bk, bv);

  /* attention: 512 blocks x 512 threads, split-K x2 in-block */
  flash_attn<<<dim3(512), dim3(512), 0, stream>>>(ws);

  /* output projection -> f32 d_out: flat 512 blocks, panel-colocating swizzle */
  gemm_out<<<dim3(512), dim3(256), 0, stream>>>(ws, bo, out);
}